// Round 19
// baseline (123.736 us; speedup 1.0000x reference)
//
#include <hip/hip_runtime.h>
#include <math.h>

#define BB   256
#define NPER 256
#define NN   (BB*NPER)
#define HH   128
#define DDIM 384
#define KK   30
#define SPD  388
#define ASTR 264          // 66 dwords -> 2-way bank alias (free)
#define ABYTES 67584
#define GASZ 65536        // per-graph tiled A in global
#define XSTR 384          // x holds all 3 layers (paired cols, sort-invariant)

#define PREP_SMEM (ABYTES + 2048)

// k_layers LDS: HT 32K + ns 1K + nd 1K + z 1K = 35840 (< 64K residency threshold?)
#define L_NSOFF 32768
#define L_NDOFF 33792
#define L_ZSOFF 34816
#define L_SMEM  35840

#define HEAD_SMEM 51712

typedef _Float16 half8 __attribute__((ext_vector_type(8)));
typedef float f32x16 __attribute__((ext_vector_type(16)));

__device__ __forceinline__ float ftanh(float x) {
    float ax = fabsf(x);
    float e = __expf(-2.f * ax);
    float r = (1.f - e) / (1.f + e);
    return copysignf(r, x);
}

// swap bits 2<->3: MFMA k-group permutation (validated bit-exact r6-r17)
__device__ __forceinline__ int sig(int s) {
    return (s & ~12) | ((s & 4) << 1) | ((s & 8) >> 1);
}

// cross-lane xor exchange; DPP for 1/2/8 (VALU pipe), ds_swizzle 4/16, shfl 32.
template <int D>
__device__ __forceinline__ float shx(float v) {
    int xx = __float_as_int(v);
    int r;
    if constexpr (D == 1)       r = __builtin_amdgcn_update_dpp(0, xx, 0xB1, 0xF, 0xF, true);   // quad_perm [1,0,3,2]
    else if constexpr (D == 2)  r = __builtin_amdgcn_update_dpp(0, xx, 0x4E, 0xF, 0xF, true);   // quad_perm [2,3,0,1]
    else if constexpr (D == 8)  r = __builtin_amdgcn_update_dpp(0, xx, 0x128, 0xF, 0xF, true);  // row_ror:8 == xor8
    else if constexpr (D == 4)  r = __builtin_amdgcn_ds_swizzle(xx, 0x101F);                     // xor4
    else if constexpr (D == 16) r = __builtin_amdgcn_ds_swizzle(xx, 0x401F);                     // xor16
    else                        return __shfl_xor(v, D, 64);
    return __int_as_float(r);
}

// ============ kernel 0: A build + norms -> global (once per graph) ============
__global__ __launch_bounds__(512, 2) void k_prep(
        const int* __restrict__ src, const int* __restrict__ dst,
        unsigned char* __restrict__ gA, float* __restrict__ nsnd) {
    extern __shared__ char smem[];
    unsigned char* As = (unsigned char*)smem;          // 256 x 264 u8
    int* scr = (int*)(smem + ABYTES);
    int* degi = scr; int* dego = scr + 256;
    const int t = threadIdx.x, g = blockIdx.x;
    {
        int4 zz = {0, 0, 0, 0};
        for (int i = t; i < ABYTES / 16; i += 512) ((int4*)smem)[i] = zz;
    }
    if (t < 256) { degi[t] = 0; dego[t] = 0; }
    __syncthreads();
    for (int e = t; e < 4096; e += 512) {
        int s = src[g * 4096 + e] & 255;      // local ids by construction
        int d = dst[g * 4096 + e] & 255;
        atomicAdd(&dego[s], 1);
        atomicAdd(&degi[d], 1);
        int off = d * ASTR + sig(s);
        atomicAdd((unsigned*)(As + (off & ~3)), 1u << ((off & 3) * 8));
    }
    __syncthreads();
    if (t < 256) {
        nsnd[g * NPER + t]      = rsqrtf((float)max(dego[t], 1)) * 4096.f;           // ns*2^12
        nsnd[NN + g * NPER + t] = rsqrtf((float)max(degi[t], 1)) * 0.000244140625f;  // nd*2^-12
    }
    // write tiled A: chunk c = rs*1024 + ks*64 + hl*32 + l31, 8B each (kloop-coalesced)
    unsigned char* gAb = gA + (size_t)g * GASZ;
    for (int c = t; c < 8192; c += 512) {
        int l31c = c & 31, hlc = (c >> 5) & 1, ksc = (c >> 6) & 15, rsc = c >> 10;
        *(uint2*)(gAb + c * 8) =
            *(const uint2*)(As + (rsc * 32 + l31c) * ASTR + ksc * 16 + hlc * 8);
    }
}

// ============ kernel 1: GraphConv layers, feature-split, 35.8K LDS ============
__global__ __launch_bounds__(512, 2) void k_layers(
        const int* __restrict__ z, const unsigned char* __restrict__ gA,
        const float* __restrict__ nsnd, const float* __restrict__ zt,
        const float* __restrict__ biases,
        float* __restrict__ x, float* __restrict__ nmaxP) {
    extern __shared__ char smem[];
    char* HT    = smem;                                // 64 rows x 512B f16 (one term)
    float* ns_s = (float*)(smem + L_NSOFF);
    float* nd_s = (float*)(smem + L_NDOFF);
    int*   z_s  = (int*)(smem + L_ZSOFF);

    const int t = threadIdx.x;
    const int g = blockIdx.x >> 1, half = blockIdx.x & 1;
    const int vbase = g * NPER, F0 = half * 64;
    const int l31 = t & 31, hl = (t >> 5) & 1, rs = t >> 6;
    const int xorf = l31 << 4;
    const int bR0  = l31 * 512;                        // ct=0 rows; ct=1 at +16384

    if (t < 256) {
        ns_s[t] = nsnd[vbase + t];
        nd_s[t] = nsnd[NN + vbase + t];
        z_s[t]  = z[vbase + t];
    }
    // A slice from gA, coalesced (512B per wave per ks), once
    const unsigned char* gBase = gA + (size_t)g * GASZ + rs * 8192 + hl * 256 + l31 * 8;
    uint2 A2[16];
    #pragma unroll
    for (int ks = 0; ks < 16; ++ks)
        A2[ks] = *(const uint2*)(gBase + ks * 512);
    __syncthreads();

    // h0 (unscaled) into C-layout regs: this block's 64 feats
    float h[2][16];
    #pragma unroll
    for (int ct = 0; ct < 2; ++ct) {
        #pragma unroll
        for (int r = 0; r < 16; ++r) {
            int d = rs * 32 + (r & 3) + 8 * (r >> 2) + 4 * hl;
            h[ct][r] = zt[(size_t)z_s[d] * HH + F0 + ct * 32 + l31];
        }
    }

    float rmax[16];
    const half8 k1024 = {(_Float16)1024.f, (_Float16)1024.f, (_Float16)1024.f, (_Float16)1024.f,
                         (_Float16)1024.f, (_Float16)1024.f, (_Float16)1024.f, (_Float16)1024.f};

    for (int l = 0; l < 3; ++l) {
        float bias0 = biases[l * HH + F0 + l31];
        float bias1 = biases[l * HH + F0 + 32 + l31];
        f32x16 acc0 = {}, acc1 = {};

        auto writeTerm = [&](bool lo) {
            #pragma unroll
            for (int ct = 0; ct < 2; ++ct) {
                int rowb = (ct * 32 + l31) * 512;
                #pragma unroll
                for (int qp = 0; qp < 2; ++qp) {
                    union { _Float16 hx[8]; int4 u; } P;
                    #pragma unroll
                    for (int jj = 0; jj < 8; ++jj) {
                        int q = 2 * qp + (jj >> 2), j = jj & 3;
                        int r = 4 * q + j;
                        int d = rs * 32 + 8 * q + 4 * hl + j;
                        float v4 = h[ct][r] * ns_s[d];       // h * ns * 2^12
                        _Float16 hv = (_Float16)v4;
                        P.hx[jj] = lo ? (_Float16)(v4 - (float)hv) : hv;
                    }
                    int off = (rs * 64 + qp * 32 + hl * 16) ^ xorf;
                    *(int4*)(HT + rowb + off) = P.u;
                }
            }
        };
        auto kloop = [&]() {
            #pragma unroll
            for (int ks = 0; ks < 16; ++ks) {
                uint2 aw = A2[ks];
                union { unsigned u[4]; half8 v; } au;
                au.u[0] = __builtin_amdgcn_perm(0x64646464u, aw.x, 0x05010400u);
                au.u[1] = __builtin_amdgcn_perm(0x64646464u, aw.x, 0x05030402u);
                au.u[2] = __builtin_amdgcn_perm(0x64646464u, aw.y, 0x05010400u);
                au.u[3] = __builtin_amdgcn_perm(0x64646464u, aw.y, 0x05030402u);
                half8 a = au.v - k1024;       // exact: (1024+b) - 1024
                int kb = (ks * 32 + hl * 16) ^ xorf;
                half8 b0 = *(const half8*)(HT + bR0 + kb);
                half8 b1 = *(const half8*)(HT + bR0 + 16384 + kb);
                acc0 = __builtin_amdgcn_mfma_f32_32x32x16_f16(a, b0, acc0, 0, 0, 0);
                acc1 = __builtin_amdgcn_mfma_f32_32x32x16_f16(a, b1, acc1, 0, 0, 0);
            }
        };

        __syncthreads();                      // prior kloop reads done
        writeTerm(false);                     // HI term
        __syncthreads();
        kloop();
        __syncthreads();
        writeTerm(true);                      // LO term
        __syncthreads();
        kloop();                              // acc = A*(H+L) = A*h*ns*2^12

        // epilogue: tanh(acc*nd*2^-12 + bias); x store; rmax
        #pragma unroll
        for (int r = 0; r < 16; ++r) {
            int d = rs * 32 + (r & 3) + 8 * (r >> 2) + 4 * hl;
            float ndv = nd_s[d];
            float t0 = ftanh(acc0[r] * ndv + bias0);
            float t1 = ftanh(acc1[r] * ndv + bias1);
            h[0][r] = t0; h[1][r] = t1;
            size_t xb = (size_t)(vbase + d) * XSTR + (size_t)l * HH + F0 + 2 * l31;
            *(float2*)&x[xb] = make_float2(t0, t1);
            float mv = fmaxf(t0, t1);
            rmax[r] = l ? fmaxf(rmax[r], mv) : mv;
        }
    }

    // per-node partial max -> nmaxP
    #pragma unroll
    for (int r = 0; r < 16; ++r) {
        float mv = rmax[r];
        mv = fmaxf(mv, shx<16>(mv));
        mv = fmaxf(mv, shx<8>(mv));
        mv = fmaxf(mv, shx<4>(mv));
        mv = fmaxf(mv, shx<2>(mv));
        mv = fmaxf(mv, shx<1>(mv));
        if (l31 == 0) {
            int d = rs * 32 + (r & 3) + 8 * (r >> 2) + 4 * hl;
            nmaxP[(size_t)half * NN + vbase + d] = mv;
        }
    }
}

// ============ kernel 2: top-30 by rank count ============
__global__ __launch_bounds__(256) void k_topk(const float* __restrict__ nmaxP,
                                              int* __restrict__ sel) {
    __shared__ float vals[NPER];
    int t = threadIdx.x, g = blockIdx.x, v = g * NPER + t;
    float m = fmaxf(nmaxP[v], nmaxP[NN + v]);
    vals[t] = m;
    __syncthreads();
    int rank = 0;
    for (int u = 0; u < NPER; ++u) {
        float uv = vals[u];
        rank += (uv > m) || (uv == m && u < t);
    }
    if (rank < KK) sel[g * KK + rank] = t;   // local node index
}

// ============ kernel 3: per-row register bitonic sort ============
__global__ __launch_bounds__(256) void k_sort(
        const float* __restrict__ x, const int* __restrict__ sel,
        float* __restrict__ pooled) {
    int lane = threadIdx.x & 63, wid = threadIdx.x >> 6;
    int bk = blockIdx.x * 4 + wid;            // row id 0..7679
    int g = bk / KK;
    int n = sel[bk];
    float v[8];
    int e0 = lane * 8;
    if (e0 < DDIM) {
        const float* xr = &x[(size_t)(g * NPER + n) * XSTR + e0];
        float4 a4 = *(const float4*)xr;
        float4 b4 = *(const float4*)(xr + 4);
        v[0] = a4.x; v[1] = a4.y; v[2] = a4.z; v[3] = a4.w;
        v[4] = b4.x; v[5] = b4.y; v[6] = b4.z; v[7] = b4.w;
    } else {
        #pragma unroll
        for (int r = 0; r < 8; ++r) v[r] = INFINITY;
    }
    #define CSW(a, b, u) { float lo = fminf(v[a], v[b]), hi = fmaxf(v[a], v[b]); \
                           v[a] = (u) ? lo : hi; v[b] = (u) ? hi : lo; }
    #define CSWB(up) CSW(0,4,up) CSW(1,5,up) CSW(2,6,up) CSW(3,7,up) \
                     CSW(0,2,up) CSW(1,3,up) CSW(4,6,up) CSW(5,7,up) \
                     CSW(0,1,up) CSW(2,3,up) CSW(4,5,up) CSW(6,7,up)
    #define SHROUND(D, up) { bool km_ = (((lane & (D)) == 0) == (up)); \
        _Pragma("unroll") \
        for (int r_ = 0; r_ < 8; ++r_) { float pv_ = shx<D>(v[r_]); \
            v[r_] = km_ ? fminf(v[r_], pv_) : fmaxf(v[r_], pv_); } }
    CSW(0,1,true) CSW(2,3,false) CSW(4,5,true) CSW(6,7,false)
    CSW(0,2,true) CSW(1,3,true) CSW(4,6,false) CSW(5,7,false)
    CSW(0,1,true) CSW(2,3,true) CSW(4,5,false) CSW(6,7,false)
    {
        bool u8 = ((lane & 1) == 0);
        CSW(0,4,u8) CSW(1,5,u8) CSW(2,6,u8) CSW(3,7,u8)
        CSW(0,2,u8) CSW(1,3,u8) CSW(4,6,u8) CSW(5,7,u8)
        CSW(0,1,u8) CSW(2,3,u8) CSW(4,5,u8) CSW(6,7,u8)
    }
    { bool up = ((lane & 2) == 0);  SHROUND(1, up) CSWB(up) }
    { bool up = ((lane & 4) == 0);  SHROUND(2, up) SHROUND(1, up) CSWB(up) }
    { bool up = ((lane & 8) == 0);  SHROUND(4, up) SHROUND(2, up) SHROUND(1, up) CSWB(up) }
    { bool up = ((lane & 16) == 0); SHROUND(8, up) SHROUND(4, up) SHROUND(2, up) SHROUND(1, up) CSWB(up) }
    { bool up = ((lane & 32) == 0); SHROUND(16, up) SHROUND(8, up) SHROUND(4, up) SHROUND(2, up) SHROUND(1, up) CSWB(up) }
    { bool up = true;               SHROUND(32, up) SHROUND(16, up) SHROUND(8, up) SHROUND(4, up) SHROUND(2, up) SHROUND(1, up) CSWB(up) }
    #undef SHROUND
    #undef CSWB
    #undef CSW
    if (e0 < DDIM) {
        float* pr = pooled + (size_t)bk * DDIM + e0;
        *(float4*)pr = make_float4(v[0], v[1], v[2], v[3]);
        *(float4*)(pr + 4) = make_float4(v[4], v[5], v[6], v[7]);
    }
}

// ============ kernel 4: head (conv1 -> maxpool -> conv2 -> lin1 -> lin2) ============
__global__ __launch_bounds__(512) void k_head(
        const float* __restrict__ pooled,
        const float* __restrict__ w1, const float* __restrict__ b1,
        const float* __restrict__ w2, const float* __restrict__ b2,
        const float* __restrict__ l1w, const float* __restrict__ l1b,
        const float* __restrict__ l2w, const float* __restrict__ l2b,
        float* __restrict__ out) {
    __shared__ float tile[KK * SPD];
    __shared__ float c1s[16 * KK];
    __shared__ float pp[16 * 15];
    __shared__ float fl[352];
    __shared__ float h1[HH];
    int t = threadIdx.x, g = blockIdx.x;
    const float4* pg = (const float4*)(pooled + (size_t)g * KK * DDIM);
    for (int i = t; i < KK * 96; i += 512) {
        int rr = i / 96, f4 = i % 96;
        ((float4*)(tile + rr * SPD))[f4] = pg[rr * 96 + f4];
    }
    __syncthreads();
    if (t < 480) {
        int o = t & 15, k2 = t >> 4;
        const float4* wr = (const float4*)(w1 + o * DDIM);
        const float4* pr = (const float4*)(tile + k2 * SPD);
        float acc = b1[o];
        #pragma unroll 4
        for (int d4 = 0; d4 < 96; ++d4) {
            float4 a = pr[d4], b = wr[d4];
            acc += a.x * b.x + a.y * b.y + a.z * b.z + a.w * b.w;
        }
        c1s[o * KK + k2] = fmaxf(acc, 0.f);
    }
    __syncthreads();
    if (t < 240) {
        int o = t / 15, j = t % 15;
        pp[t] = fmaxf(c1s[o * KK + 2 * j], c1s[o * KK + 2 * j + 1]);
    }
    __syncthreads();
    if (t < 352) {
        int c = t / 11, tt = t % 11;
        float acc = b2[c];
        for (int i = 0; i < 16; ++i) {
            #pragma unroll
            for (int u = 0; u < 5; ++u)
                acc += pp[i * 15 + tt + u] * w2[(c * 16 + i) * 5 + u];
        }
        fl[t] = fmaxf(acc, 0.f);
    }
    __syncthreads();
    if (t < 128) {
        const float4* wr = (const float4*)(l1w + t * 352);
        const float4* fr = (const float4*)fl;
        float acc = l1b[t];
        #pragma unroll 4
        for (int i = 0; i < 88; ++i) {
            float4 a = fr[i], b = wr[i];
            acc += a.x * b.x + a.y * b.y + a.z * b.z + a.w * b.w;
        }
        h1[t] = fmaxf(acc, 0.f);
    }
    __syncthreads();
    if (t < 64) {
        float v2 = h1[t] * l2w[t] + h1[t + 64] * l2w[t + 64];
        for (int s2 = 32; s2 > 0; s2 >>= 1) v2 += __shfl_down(v2, s2);
        if (t == 0) out[g] = v2 + l2b[0];
    }
}

extern "C" void kernel_launch(void* const* d_in, const int* in_sizes, int n_in,
                              void* d_out, int out_size, void* d_ws, size_t ws_size,
                              hipStream_t stream) {
    const int*   z      = (const int*)d_in[0];
    const int*   src    = (const int*)d_in[1];
    const int*   dst    = (const int*)d_in[2];
    const float* zt     = (const float*)d_in[3];
    const float* biases = (const float*)d_in[4];
    const float* w1     = (const float*)d_in[5];
    const float* b1     = (const float*)d_in[6];
    const float* w2     = (const float*)d_in[7];
    const float* b2     = (const float*)d_in[8];
    const float* l1w    = (const float*)d_in[9];
    const float* l1b    = (const float*)d_in[10];
    const float* l2w    = (const float*)d_in[11];
    const float* l2b    = (const float*)d_in[12];
    float* out = (float*)d_out;

    char* ws = (char*)d_ws;
    size_t ofs = 0;
    auto alloc = [&](size_t bytes) -> void* {
        void* p = ws + ofs;
        ofs += (bytes + 255) & ~(size_t)255;
        return p;
    };
    float* x      = (float*)alloc((size_t)NN * XSTR * 4);        // 96 MB
    float* nmaxP  = (float*)alloc((size_t)2 * NN * 4);           // 512 KB
    float* pooled = (float*)alloc((size_t)BB * KK * DDIM * 4);   // 11.8 MB
    int*   sel    = (int*)alloc((size_t)BB * KK * 4);
    unsigned char* gA = (unsigned char*)alloc((size_t)BB * GASZ);  // 16 MB
    float* nsnd   = (float*)alloc((size_t)2 * NN * 4);           // 512 KB

    hipFuncSetAttribute((const void*)k_prep,
                        hipFuncAttributeMaxDynamicSharedMemorySize, PREP_SMEM);
    hipFuncSetAttribute((const void*)k_layers,
                        hipFuncAttributeMaxDynamicSharedMemorySize, L_SMEM);

    k_prep<<<BB, 512, PREP_SMEM, stream>>>(src, dst, gA, nsnd);
    k_layers<<<2 * BB, 512, L_SMEM, stream>>>(z, gA, nsnd, zt, biases, x, nmaxP);
    k_topk<<<BB, 256, 0, stream>>>(nmaxP, sel);
    k_sort<<<BB * KK / 4, 256, 0, stream>>>(x, sel, pooled);
    k_head<<<BB, 512, 0, stream>>>(pooled, w1, b1, w2, b2, l1w, l1b, l2w, l2b, out);
}

// Round 21
// 107.851 us; speedup vs baseline: 1.1473x; 1.1473x over previous
//
#include <hip/hip_runtime.h>
#include <math.h>

#define BB   256
#define NPER 256
#define NN   (BB*NPER)
#define HH   128
#define DDIM 384
#define KK   30
#define SPD  388
#define ASTR 264          // 66 dwords -> 2-way bank alias (free)
#define ABYTES 67584
#define XSTR 256          // x keeps layers 0,1 (layer 2 -> pl2 compact)

#define HTHOFF 67584
#define NSOFF  133120
#define NDOFF  134144
#define NMOFF  135168
#define RNKOFF 136192
#define SCROFF 137216
#define SMEM_SZ 140288

typedef _Float16 half8 __attribute__((ext_vector_type(8)));
typedef float f32x16 __attribute__((ext_vector_type(16)));

__device__ __forceinline__ float ftanh(float x) {
    float ax = fabsf(x);
    float e = __expf(-2.f * ax);
    float r = (1.f - e) / (1.f + e);
    return copysignf(r, x);
}

// swap bits 2<->3: MFMA k-group permutation (validated bit-exact r6-r19)
__device__ __forceinline__ int sig(int s) {
    return (s & ~12) | ((s & 4) << 1) | ((s & 8) >> 1);
}

// cross-lane xor exchange; DPP for 1/2/8 (VALU pipe), ds_swizzle 4/16, shfl 32.
// validated passing in r16/r17.
template <int D>
__device__ __forceinline__ float shx(float v) {
    int xx = __float_as_int(v);
    int r;
    if constexpr (D == 1)       r = __builtin_amdgcn_update_dpp(0, xx, 0xB1, 0xF, 0xF, true);   // quad_perm [1,0,3,2]
    else if constexpr (D == 2)  r = __builtin_amdgcn_update_dpp(0, xx, 0x4E, 0xF, 0xF, true);   // quad_perm [2,3,0,1]
    else if constexpr (D == 8)  r = __builtin_amdgcn_update_dpp(0, xx, 0x128, 0xF, 0xF, true);  // row_ror:8 == xor8
    else if constexpr (D == 4)  r = __builtin_amdgcn_ds_swizzle(xx, 0x101F);                     // xor4
    else if constexpr (D == 16) r = __builtin_amdgcn_ds_swizzle(xx, 0x401F);                     // xor16
    else                        return __shfl_xor(v, D, 64);
    return __int_as_float(r);
}

// ============ kernel 1: GraphConv layers + topk + pl2 (1 block/graph, big LDS) ============
// 512 threads = 8 waves (launch_bounds 2nd arg = min BLOCKS/CU, CUDA semantics:
// (512,2) -> 128-reg cap, no spill — r10/r17 evidence).
__global__ __launch_bounds__(512, 2) void k_layers(
        const int* __restrict__ z, const int* __restrict__ src, const int* __restrict__ dst,
        const float* __restrict__ zt, const float* __restrict__ biases,
        float* __restrict__ x, float* __restrict__ pl2, int* __restrict__ sel) {
    extern __shared__ char smem[];
    unsigned char* As = (unsigned char*)smem;          // 256 x 264 u8 (phase 0 only)
    char* HTL = smem;                                  // 128 x 512B f16 lo (overlays As)
    char* HTH = smem + HTHOFF;                         // 128 x 512B f16 hi
    float* ns_s = (float*)(smem + NSOFF);
    float* nd_s = (float*)(smem + NDOFF);
    float* nm   = (float*)(smem + NMOFF);
    int*   rnk  = (int*)(smem + RNKOFF);
    int*   scr  = (int*)(smem + SCROFF);               // 768 ints scratch
    int* degi = scr; int* dego = scr + 256; int* z_s = scr + 512;

    const int t = threadIdx.x, g = blockIdx.x, vbase = g * NPER;
    const int l31 = t & 31, hl = (t >> 5) & 1, rs = t >> 6;
    const int xorf = l31 << 4;
    const int aRow = (rs * 32 + l31) * ASTR;
    const int bR0  = l31 * 512;                        // ct tile i at +i*16384

    // ---------------- phase 0: build A (LDS) + histograms ----------------
    {
        int4 zz = {0, 0, 0, 0};
        for (int i = t; i < ABYTES / 16; i += 512) ((int4*)smem)[i] = zz;
    }
    if (t < 256) { degi[t] = 0; dego[t] = 0; z_s[t] = z[vbase + t]; }
    __syncthreads();
    for (int e = t; e < 4096; e += 512) {
        int s = src[g * 4096 + e] & 255;      // local ids by construction
        int d = dst[g * 4096 + e] & 255;
        atomicAdd(&dego[s], 1);
        atomicAdd(&degi[d], 1);
        int off = d * ASTR + sig(s);
        atomicAdd((unsigned*)(As + (off & ~3)), 1u << ((off & 3) * 8));
    }
    // load h0 (unscaled) into C-layout registers; overlaps the atomics above
    float h[4][16];
    #pragma unroll
    for (int ct = 0; ct < 4; ++ct) {
        #pragma unroll
        for (int r = 0; r < 16; ++r) {
            int d = rs * 32 + (r & 3) + 8 * (r >> 2) + 4 * hl;
            h[ct][r] = zt[(size_t)z_s[d] * HH + ct * 32 + l31];
        }
    }
    __syncthreads();
    if (t < 256) {
        ns_s[t] = rsqrtf((float)max(dego[t], 1));
        nd_s[t] = rsqrtf((float)max(degi[t], 1));
    }

    // convert this wave's A rows u8 -> f16 registers ONCE (then As is dead)
    const half8 k1024 = {(_Float16)1024.f, (_Float16)1024.f, (_Float16)1024.f, (_Float16)1024.f,
                         (_Float16)1024.f, (_Float16)1024.f, (_Float16)1024.f, (_Float16)1024.f};
    half8 Areg[16];
    #pragma unroll
    for (int ks = 0; ks < 16; ++ks) {
        uint2 aw = *(const uint2*)(As + aRow + ks * 16 + hl * 8);
        union { unsigned u[4]; half8 v; } au;
        au.u[0] = __builtin_amdgcn_perm(0x64646464u, aw.x, 0x05010400u);
        au.u[1] = __builtin_amdgcn_perm(0x64646464u, aw.x, 0x05030402u);
        au.u[2] = __builtin_amdgcn_perm(0x64646464u, aw.y, 0x05010400u);
        au.u[3] = __builtin_amdgcn_perm(0x64646464u, aw.y, 0x05030402u);
        Areg[ks] = au.v - k1024;              // exact: (1024+b) - 1024
    }

    float rmax[16];

    // ---------------- phase 1: 3 GraphConv layers, 2-term fp16 split MFMA ----------------
    for (int l = 0; l < 3; ++l) {
        float bias_[4];
        #pragma unroll
        for (int ct = 0; ct < 4; ++ct) bias_[ct] = biases[l * HH + ct * 32 + l31];
        f32x16 acc0 = {}, acc1 = {}, acc2 = {}, acc3 = {};

        __syncthreads();                      // prior kloop reads / As conversion done
        // write BOTH split terms of (h * ns) in one pass
        #pragma unroll
        for (int ct = 0; ct < 4; ++ct) {
            int rowb = (ct * 32 + l31) * 512;
            #pragma unroll
            for (int qp = 0; qp < 2; ++qp) {
                union { _Float16 hx[8]; int4 u; } H, L;
                #pragma unroll
                for (int jj = 0; jj < 8; ++jj) {
                    int q = 2 * qp + (jj >> 2), j = jj & 3;
                    int r = 4 * q + j;
                    int d = rs * 32 + 8 * q + 4 * hl + j;
                    float v = h[ct][r] * ns_s[d];
                    _Float16 hv = (_Float16)v;
                    H.hx[jj] = hv;
                    L.hx[jj] = (_Float16)((v - (float)hv) * 4096.f);
                }
                int off = (rs * 64 + qp * 32 + hl * 16) ^ xorf;
                *(int4*)(HTH + rowb + off) = H.u;
                *(int4*)(HTL + rowb + off) = L.u;
            }
        }
        __syncthreads();

        // lo pass
        #pragma unroll
        for (int ks = 0; ks < 16; ++ks) {
            int kb = (ks * 32 + hl * 16) ^ xorf;
            half8 bb0 = *(const half8*)(HTL + bR0 + kb);
            half8 bb1 = *(const half8*)(HTL + bR0 + 16384 + kb);
            half8 bb2 = *(const half8*)(HTL + bR0 + 32768 + kb);
            half8 bb3 = *(const half8*)(HTL + bR0 + 49152 + kb);
            acc0 = __builtin_amdgcn_mfma_f32_32x32x16_f16(Areg[ks], bb0, acc0, 0, 0, 0);
            acc1 = __builtin_amdgcn_mfma_f32_32x32x16_f16(Areg[ks], bb1, acc1, 0, 0, 0);
            acc2 = __builtin_amdgcn_mfma_f32_32x32x16_f16(Areg[ks], bb2, acc2, 0, 0, 0);
            acc3 = __builtin_amdgcn_mfma_f32_32x32x16_f16(Areg[ks], bb3, acc3, 0, 0, 0);
        }
        #pragma unroll
        for (int i = 0; i < 16; ++i) {
            acc0[i] *= 0.000244140625f;       // 2^-12
            acc1[i] *= 0.000244140625f;
            acc2[i] *= 0.000244140625f;
            acc3[i] *= 0.000244140625f;
        }
        // hi pass (no barrier: HTL/HTH read-only here)
        #pragma unroll
        for (int ks = 0; ks < 16; ++ks) {
            int kb = (ks * 32 + hl * 16) ^ xorf;
            half8 bb0 = *(const half8*)(HTH + bR0 + kb);
            half8 bb1 = *(const half8*)(HTH + bR0 + 16384 + kb);
            half8 bb2 = *(const half8*)(HTH + bR0 + 32768 + kb);
            half8 bb3 = *(const half8*)(HTH + bR0 + 49152 + kb);
            acc0 = __builtin_amdgcn_mfma_f32_32x32x16_f16(Areg[ks], bb0, acc0, 0, 0, 0);
            acc1 = __builtin_amdgcn_mfma_f32_32x32x16_f16(Areg[ks], bb1, acc1, 0, 0, 0);
            acc2 = __builtin_amdgcn_mfma_f32_32x32x16_f16(Areg[ks], bb2, acc2, 0, 0, 0);
            acc3 = __builtin_amdgcn_mfma_f32_32x32x16_f16(Areg[ks], bb3, acc3, 0, 0, 0);
        }

        // epilogue: tanh -> h regs; x store as one float4 (4-col pairing, sort-invariant)
        #pragma unroll
        for (int r = 0; r < 16; ++r) {
            int d = rs * 32 + (r & 3) + 8 * (r >> 2) + 4 * hl;
            float ndv = nd_s[d];
            float t0 = ftanh(acc0[r] * ndv + bias_[0]);
            float t1 = ftanh(acc1[r] * ndv + bias_[1]);
            float t2 = ftanh(acc2[r] * ndv + bias_[2]);
            float t3 = ftanh(acc3[r] * ndv + bias_[3]);
            h[0][r] = t0; h[1][r] = t1; h[2][r] = t2; h[3][r] = t3;
            float mv = fmaxf(fmaxf(t0, t1), fmaxf(t2, t3));
            rmax[r] = l ? fmaxf(rmax[r], mv) : mv;
            if (l < 2) {
                size_t xb = (size_t)(vbase + d) * XSTR + (size_t)l * HH + 4 * l31;
                *(float4*)&x[xb] = make_float4(t0, t1, t2, t3);
            }
        }
    }

    // ---------------- phase 2: per-node max + top-30 rank ----------------
    // each wave holds ALL 128 features of its node across l31 lanes (same hl);
    // reduction is complete within the 32-lane group — NO xor32 (r20's bug).
    #pragma unroll
    for (int r = 0; r < 16; ++r) {
        float mv = rmax[r];
        mv = fmaxf(mv, shx<16>(mv));
        mv = fmaxf(mv, shx<8>(mv));
        mv = fmaxf(mv, shx<4>(mv));
        mv = fmaxf(mv, shx<2>(mv));
        mv = fmaxf(mv, shx<1>(mv));
        if (l31 == 0) nm[rs * 32 + (r & 3) + 8 * (r >> 2) + 4 * hl] = mv;
    }
    __syncthreads();
    {
        int n = t & 255, q = t >> 8;
        float mv = nm[n];
        int p = 0;
        for (int u = q * 128; u < q * 128 + 128; ++u) {
            float uv = nm[u];
            p += (uv > mv) || (uv == mv && u < n);
        }
        scr[t] = p;
    }
    __syncthreads();
    if (t < 256) {
        int rank = scr[t] + scr[t + 256];
        rnk[t] = (rank < KK) ? rank : -1;
        if (rank < KK) sel[g * KK + rank] = t;
    }
    __syncthreads();

    // ---------------- phase 3: selected layer-2 rows -> pl2 compact (from regs) ----------------
    #pragma unroll
    for (int r = 0; r < 16; ++r) {
        int d = rs * 32 + (r & 3) + 8 * (r >> 2) + 4 * hl;
        int rr = rnk[d];
        if (rr >= 0) {
            float* p = pl2 + (size_t)(g * KK + rr) * HH + 4 * l31;
            *(float4*)p = make_float4(h[0][r], h[1][r], h[2][r], h[3][r]);
        }
    }
}

// ============ kernel 2: per-row register bitonic sort (DPP/swizzle, no LDS) ============
__global__ __launch_bounds__(256) void k_sort(
        const float* __restrict__ x, const float* __restrict__ pl2,
        const int* __restrict__ sel, float* __restrict__ pooled) {
    int lane = threadIdx.x & 63, wid = threadIdx.x >> 6;
    int bk = blockIdx.x * 4 + wid;            // row id 0..7679
    int g = bk / KK;
    int n = sel[bk];
    float v[8];
    int e0 = lane * 8;
    if (e0 < 256) {
        const float* xr = &x[(size_t)(g * NPER + n) * XSTR + e0];
        float4 a4 = *(const float4*)xr;
        float4 b4 = *(const float4*)(xr + 4);
        v[0] = a4.x; v[1] = a4.y; v[2] = a4.z; v[3] = a4.w;
        v[4] = b4.x; v[5] = b4.y; v[6] = b4.z; v[7] = b4.w;
    } else if (e0 < DDIM) {
        const float* pr = &pl2[(size_t)bk * HH + (e0 - 256)];
        float4 a4 = *(const float4*)pr;
        float4 b4 = *(const float4*)(pr + 4);
        v[0] = a4.x; v[1] = a4.y; v[2] = a4.z; v[3] = a4.w;
        v[4] = b4.x; v[5] = b4.y; v[6] = b4.z; v[7] = b4.w;
    } else {
        #pragma unroll
        for (int r = 0; r < 8; ++r) v[r] = INFINITY;
    }
    #define CSW(a, b, u) { float lo = fminf(v[a], v[b]), hi = fmaxf(v[a], v[b]); \
                           v[a] = (u) ? lo : hi; v[b] = (u) ? hi : lo; }
    #define CSWB(up) CSW(0,4,up) CSW(1,5,up) CSW(2,6,up) CSW(3,7,up) \
                     CSW(0,2,up) CSW(1,3,up) CSW(4,6,up) CSW(5,7,up) \
                     CSW(0,1,up) CSW(2,3,up) CSW(4,5,up) CSW(6,7,up)
    #define SHROUND(D, up) { bool km_ = (((lane & (D)) == 0) == (up)); \
        _Pragma("unroll") \
        for (int r_ = 0; r_ < 8; ++r_) { float pv_ = shx<D>(v[r_]); \
            v[r_] = km_ ? fminf(v[r_], pv_) : fmaxf(v[r_], pv_); } }
    // in-register k2=2,4,8
    CSW(0,1,true) CSW(2,3,false) CSW(4,5,true) CSW(6,7,false)
    CSW(0,2,true) CSW(1,3,true) CSW(4,6,false) CSW(5,7,false)
    CSW(0,1,true) CSW(2,3,true) CSW(4,5,false) CSW(6,7,false)
    {
        bool u8 = ((lane & 1) == 0);
        CSW(0,4,u8) CSW(1,5,u8) CSW(2,6,u8) CSW(3,7,u8)
        CSW(0,2,u8) CSW(1,3,u8) CSW(4,6,u8) CSW(5,7,u8)
        CSW(0,1,u8) CSW(2,3,u8) CSW(4,5,u8) CSW(6,7,u8)
    }
    // cross-lane stages k2=16..512
    { bool up = ((lane & 2) == 0);  SHROUND(1, up) CSWB(up) }
    { bool up = ((lane & 4) == 0);  SHROUND(2, up) SHROUND(1, up) CSWB(up) }
    { bool up = ((lane & 8) == 0);  SHROUND(4, up) SHROUND(2, up) SHROUND(1, up) CSWB(up) }
    { bool up = ((lane & 16) == 0); SHROUND(8, up) SHROUND(4, up) SHROUND(2, up) SHROUND(1, up) CSWB(up) }
    { bool up = ((lane & 32) == 0); SHROUND(16, up) SHROUND(8, up) SHROUND(4, up) SHROUND(2, up) SHROUND(1, up) CSWB(up) }
    { bool up = true;               SHROUND(32, up) SHROUND(16, up) SHROUND(8, up) SHROUND(4, up) SHROUND(2, up) SHROUND(1, up) CSWB(up) }
    #undef SHROUND
    #undef CSWB
    #undef CSW
    if (e0 < DDIM) {
        float* pr = pooled + (size_t)bk * DDIM + e0;
        *(float4*)pr = make_float4(v[0], v[1], v[2], v[3]);
        *(float4*)(pr + 4) = make_float4(v[4], v[5], v[6], v[7]);
    }
}

// ============ kernel 3: head (conv1 -> maxpool -> conv2 -> lin1 -> lin2) ============
__global__ __launch_bounds__(512) void k_head(
        const float* __restrict__ pooled,
        const float* __restrict__ w1, const float* __restrict__ b1,
        const float* __restrict__ w2, const float* __restrict__ b2,
        const float* __restrict__ l1w, const float* __restrict__ l1b,
        const float* __restrict__ l2w, const float* __restrict__ l2b,
        float* __restrict__ out) {
    __shared__ float tile[KK * SPD];
    __shared__ float c1s[16 * KK];
    __shared__ float pp[16 * 15];
    __shared__ float fl[352];
    __shared__ float h1[HH];
    int t = threadIdx.x, g = blockIdx.x;
    const float4* pg = (const float4*)(pooled + (size_t)g * KK * DDIM);
    for (int i = t; i < KK * 96; i += 512) {
        int rr = i / 96, f4 = i % 96;
        ((float4*)(tile + rr * SPD))[f4] = pg[rr * 96 + f4];
    }
    __syncthreads();
    if (t < 480) {
        int o = t & 15, k2 = t >> 4;
        const float4* wr = (const float4*)(w1 + o * DDIM);
        const float4* pr = (const float4*)(tile + k2 * SPD);
        float acc = b1[o];
        #pragma unroll 4
        for (int d4 = 0; d4 < 96; ++d4) {
            float4 a = pr[d4], b = wr[d4];
            acc += a.x * b.x + a.y * b.y + a.z * b.z + a.w * b.w;
        }
        c1s[o * KK + k2] = fmaxf(acc, 0.f);
    }
    __syncthreads();
    if (t < 240) {
        int o = t / 15, j = t % 15;
        pp[t] = fmaxf(c1s[o * KK + 2 * j], c1s[o * KK + 2 * j + 1]);
    }
    __syncthreads();
    if (t < 352) {
        int c = t / 11, tt = t % 11;
        float acc = b2[c];
        for (int i = 0; i < 16; ++i) {
            #pragma unroll
            for (int u = 0; u < 5; ++u)
                acc += pp[i * 15 + tt + u] * w2[(c * 16 + i) * 5 + u];
        }
        fl[t] = fmaxf(acc, 0.f);
    }
    __syncthreads();
    if (t < 128) {
        const float4* wr = (const float4*)(l1w + t * 352);
        const float4* fr = (const float4*)fl;
        float acc = l1b[t];
        #pragma unroll 4
        for (int i = 0; i < 88; ++i) {
            float4 a = fr[i], b = wr[i];
            acc += a.x * b.x + a.y * b.y + a.z * b.z + a.w * b.w;
        }
        h1[t] = fmaxf(acc, 0.f);
    }
    __syncthreads();
    if (t < 64) {
        float v2 = h1[t] * l2w[t] + h1[t + 64] * l2w[t + 64];
        for (int s2 = 32; s2 > 0; s2 >>= 1) v2 += __shfl_down(v2, s2);
        if (t == 0) out[g] = v2 + l2b[0];
    }
}

extern "C" void kernel_launch(void* const* d_in, const int* in_sizes, int n_in,
                              void* d_out, int out_size, void* d_ws, size_t ws_size,
                              hipStream_t stream) {
    const int*   z      = (const int*)d_in[0];
    const int*   src    = (const int*)d_in[1];
    const int*   dst    = (const int*)d_in[2];
    const float* zt     = (const float*)d_in[3];
    const float* biases = (const float*)d_in[4];
    const float* w1     = (const float*)d_in[5];
    const float* b1     = (const float*)d_in[6];
    const float* w2     = (const float*)d_in[7];
    const float* b2     = (const float*)d_in[8];
    const float* l1w    = (const float*)d_in[9];
    const float* l1b    = (const float*)d_in[10];
    const float* l2w    = (const float*)d_in[11];
    const float* l2b    = (const float*)d_in[12];
    float* out = (float*)d_out;
    char* ws = (char*)d_ws;
    float* x      = (float*)ws;                                     // 64 MB: layers 0,1
    float* pl2    = (float*)(ws + (size_t)NN * XSTR * 4);           // 3.9 MB
    float* pooled = (float*)(ws + (size_t)NN * XSTR * 4 + (size_t)BB * KK * HH * 4);  // 11.8 MB
    int*   sel    = (int*)(ws + (size_t)NN * XSTR * 4 + (size_t)BB * KK * HH * 4
                              + (size_t)BB * KK * DDIM * 4);

    hipFuncSetAttribute((const void*)k_layers,
                        hipFuncAttributeMaxDynamicSharedMemorySize, SMEM_SZ);

    k_layers<<<BB, 512, SMEM_SZ, stream>>>(z, src, dst, zt, biases, x, pl2, sel);
    k_sort<<<BB * KK / 4, 256, 0, stream>>>(x, pl2, sel, pooled);
    k_head<<<BB, 512, 0, stream>>>(pooled, w1, b1, w2, b2, l1w, l1b, l2w, l2b, out);
}